// Round 1
// 601.886 us; speedup vs baseline: 1.0952x; 1.0952x over previous
//
#include <hip/hip_runtime.h>
#include <hip/hip_bf16.h>

#define L_SEQ 4096
#define BATCH 8
#define DMODEL 1024
#define NHEAD 16
#define DHEAD 64
#define NSAMP 128

typedef __attribute__((ext_vector_type(8))) short short8;
typedef __attribute__((ext_vector_type(4))) float f32x4;

static __device__ __forceinline__ unsigned short f2bf(float f) {
    union { float f; unsigned int u; } x; x.f = f;
    unsigned int r = (x.u + 0x7fffu + ((x.u >> 16) & 1u)) >> 16;
    return (unsigned short)r;
}

// async global->LDS, 16B per lane; LDS dest must be wave-uniform-base + lane*16
static __device__ __forceinline__ void gld_lds16(const unsigned short* g,
                                                 unsigned short* l) {
    __builtin_amdgcn_global_load_lds(
        (const __attribute__((address_space(1))) void*)g,
        (__attribute__((address_space(3))) void*)l, 16, 0, 0);
}

// ---------------- elementwise f32 -> bf16 convert (float4 granularity) ------
__global__ void conv_bf16_kernel(const float* __restrict__ src,
                                 unsigned short* __restrict__ dst, int n4) {
    int idx = blockIdx.x * blockDim.x + threadIdx.x;
    if (idx < n4) {
        float4 v = ((const float4*)src)[idx];
        uint2 pk;
        pk.x = (unsigned)f2bf(v.x) | ((unsigned)f2bf(v.y) << 16);
        pk.y = (unsigned)f2bf(v.z) | ((unsigned)f2bf(v.w) << 16);
        ((uint2*)dst)[idx] = pk;
    }
}

// ---------------- gather rows of k/v by sampled_index -> bf16 ---------------
__global__ void gather_bf16_kernel(const float* __restrict__ src,
                                   const int* __restrict__ smp,
                                   unsigned short* __restrict__ dst, int total8) {
    int idx = blockIdx.x * blockDim.x + threadIdx.x;
    if (idx < total8) {
        int s = idx >> 10;
        int rem = idx & 1023;
        const float* g = src + (size_t)smp[s] * (BATCH * DMODEL) + rem * 8;
        float4 v0 = *(const float4*)g;
        float4 v1 = *(const float4*)(g + 4);
        uint4 pk;
        pk.x = (unsigned)f2bf(v0.x) | ((unsigned)f2bf(v0.y) << 16);
        pk.y = (unsigned)f2bf(v0.z) | ((unsigned)f2bf(v0.w) << 16);
        pk.z = (unsigned)f2bf(v1.x) | ((unsigned)f2bf(v1.y) << 16);
        pk.w = (unsigned)f2bf(v1.z) | ((unsigned)f2bf(v1.w) << 16);
        *(uint4*)&dst[(size_t)idx * 8] = pk;
    }
}

// ---------------- modify_key_length ----------------------------------------
__global__ void mkl_kernel(const int* __restrict__ smp,
                           const int* __restrict__ klen, int* __restrict__ mkl) {
    int b = threadIdx.x;
    if (b < BATCH) {
        int kl = klen[b];
        int c = 0;
        for (int s = 0; s < NSAMP; ++s) c += (smp[s] < kl) ? 1 : 0;
        mkl[b] = c;
    }
}

// ---------------- old 128x128 NT GEMM body (kept for small K/V proj) -------
template <bool OUT_F32>
static __device__ __forceinline__ void gemm_body(
    const unsigned short* __restrict__ A, const unsigned short* __restrict__ Bw,
    const float* __restrict__ bias, void* __restrict__ Cp,
    int m0, int n0, int N, int K,
    unsigned short* lA, unsigned short* lB) {
    const int t = threadIdx.x;
    const int wave = t >> 6;
    const int lane = t & 63;
    const int l16 = lane & 15;
    const int quad = lane >> 4;
    const int wm = (wave >> 1) * 64;
    const int wn = (wave & 1) * 64;

    f32x4 acc[4][4];
    #pragma unroll
    for (int i = 0; i < 4; ++i)
        #pragma unroll
        for (int j = 0; j < 4; ++j)
            acc[i][j] = f32x4{0.f, 0.f, 0.f, 0.f};

    const int lin0 = t * 8;
    const int wbase = (t & ~63) * 8;

    for (int k0 = 0; k0 < K; k0 += 64) {
        #pragma unroll
        for (int p = 0; p < 4; ++p) {
            int lin = p * 2048 + lin0;
            int row = lin >> 6, col = lin & 63;
            gld_lds16(A + (size_t)(m0 + row) * K + k0 + col, lA + p * 2048 + wbase);
        }
        #pragma unroll
        for (int p = 0; p < 4; ++p) {
            int lin = p * 2048 + lin0;
            int row = lin >> 6, col = lin & 63;
            gld_lds16(Bw + (size_t)(n0 + row) * K + k0 + col, lB + p * 2048 + wbase);
        }
        __syncthreads();

        #pragma unroll
        for (int kk = 0; kk < 64; kk += 32) {
            short8 af[4], bfr[4];
            #pragma unroll
            for (int mt = 0; mt < 4; ++mt)
                af[mt] = *(const short8*)&lA[(wm + mt * 16 + l16) * 64 + kk + quad * 8];
            #pragma unroll
            for (int nt = 0; nt < 4; ++nt)
                bfr[nt] = *(const short8*)&lB[(wn + nt * 16 + l16) * 64 + kk + quad * 8];
            #pragma unroll
            for (int mt = 0; mt < 4; ++mt)
                #pragma unroll
                for (int nt = 0; nt < 4; ++nt)
                    acc[mt][nt] = __builtin_amdgcn_mfma_f32_16x16x32_bf16(
                        af[mt], bfr[nt], acc[mt][nt], 0, 0, 0);
        }
        __syncthreads();
    }

    #pragma unroll
    for (int mt = 0; mt < 4; ++mt) {
        #pragma unroll
        for (int nt = 0; nt < 4; ++nt) {
            int col = n0 + wn + nt * 16 + l16;
            float bv = bias[col];
            #pragma unroll
            for (int r = 0; r < 4; ++r) {
                int row = m0 + wm + mt * 16 + quad * 4 + r;
                float val = acc[mt][nt][r] + bv;
                if (OUT_F32)
                    ((float*)Cp)[(size_t)row * N + col] = val;
                else
                    ((unsigned short*)Cp)[(size_t)row * N + col] = f2bf(val);
            }
        }
    }
}

// fused K/V projection: z=0 -> kp, z=1 -> vp (small M=1024; old path)
__global__ __launch_bounds__(256) void gemm_kv(
    const unsigned short* __restrict__ Ak, const unsigned short* __restrict__ Av,
    const unsigned short* __restrict__ Bk, const unsigned short* __restrict__ Bv,
    const float* __restrict__ bk, const float* __restrict__ bv,
    unsigned short* __restrict__ Ck, unsigned short* __restrict__ Cv) {
    __shared__ __align__(16) unsigned short lA[128 * 64];
    __shared__ __align__(16) unsigned short lB[128 * 64];
    if (blockIdx.z == 0)
        gemm_body<false>(Ak, Bk, bk, Ck, blockIdx.x * 128, blockIdx.y * 128,
                         DMODEL, DMODEL, lA, lB);
    else
        gemm_body<false>(Av, Bv, bv, Cv, blockIdx.x * 128, blockIdx.y * 128,
                         DMODEL, DMODEL, lA, lB);
}

// ---------------- 256x256 deep-pipelined NT GEMM, BK=32, ring-4 LDS --------
// M = 32768, N = K = 1024 fixed. 512 threads = 8 waves (2 M x 4 N), wave tile
// 128x64. LDS [256][32] bf16 per matrix: row stride 64 B -> 8 consecutive rows
// sweep all 32 banks -> ds_read_b128 fragment reads are conflict-free without
// swizzle (so global_load_lds keeps its linear destination).
// Pipeline: prefetch depth 3 into 4 slots; per K-tile exactly one counted
// s_waitcnt vmcnt(8) + one raw s_barrier (never drain to 0 in steady state).
// WAR-safe: stage(t+3) targets slot (t-1)&3 and is issued AFTER barrier(t);
// every wave's reads of tile t-1 were consumed by its MFMAs (lgkmcnt) before
// it reached barrier(t).
#define GNT 32   // K / 32

template <bool OUT_F32>
__global__ __launch_bounds__(512, 2) void gemm256_kernel(
    const unsigned short* __restrict__ A, const unsigned short* __restrict__ Bw,
    const float* __restrict__ bias, void* __restrict__ Cp)
{
    __shared__ __align__(16) unsigned short ls[4][2][8192];  // 128 KiB

    // XCD-aware bijective swizzle: 512 blocks = 8 XCDs x 64; each XCD gets a
    // contiguous chunk of 16 M-tiles x 4 N-tiles (A-tile reused 4x in its L2).
    const int bid = blockIdx.x;
    const int swz = (bid & 7) * 64 + (bid >> 3);
    const int m0 = (swz >> 2) * 256;
    const int n0 = (swz & 3) * 256;

    const int t = threadIdx.x;
    const int wave = t >> 6, lane = t & 63;
    const int l16 = lane & 15, quad = lane >> 4;
    const int wm = wave >> 2, wn = wave & 3;
    const int wb = wave * 512;                  // wave-uniform LDS base (elems)

    // staging source: thread t covers rows t>>2 (+128), cols (t&3)*8 .. +7
    const int srow = t >> 2;
    const int scol = (t & 3) * 8;
    const unsigned short* a0 = A + (size_t)(m0 + srow) * DMODEL + scol;
    const unsigned short* a1 = a0 + (size_t)128 * DMODEL;
    const unsigned short* b0 = Bw + (size_t)(n0 + srow) * DMODEL + scol;
    const unsigned short* b1 = b0 + (size_t)128 * DMODEL;

    #define STAGE(tk, s) do {                                   \
        gld_lds16(a0 + (tk) * 32, &ls[s][0][wb]);               \
        gld_lds16(a1 + (tk) * 32, &ls[s][0][4096 + wb]);        \
        gld_lds16(b0 + (tk) * 32, &ls[s][1][wb]);               \
        gld_lds16(b1 + (tk) * 32, &ls[s][1][4096 + wb]);        \
    } while (0)

    STAGE(0, 0); STAGE(1, 1); STAGE(2, 2);

    f32x4 acc[8][4];
    #pragma unroll
    for (int i = 0; i < 8; ++i)
        #pragma unroll
        for (int j = 0; j < 4; ++j)
            acc[i][j] = f32x4{0.f, 0.f, 0.f, 0.f};

    const int aoff = (wm * 128 + l16) * 32 + quad * 8;   // + mt*512
    const int boff = (wn * 64 + l16) * 32 + quad * 8;    // + nt*512

    #pragma unroll
    for (int tk = 0; tk < GNT; ++tk) {
        // counted vmcnt: tiles tk+1, tk+2 (4 loads each) may stay in flight
        if (tk < GNT - 2)
            asm volatile("s_waitcnt vmcnt(8)" ::: "memory");
        else if (tk == GNT - 2)
            asm volatile("s_waitcnt vmcnt(4)" ::: "memory");
        else
            asm volatile("s_waitcnt vmcnt(0)" ::: "memory");
        __builtin_amdgcn_s_barrier();

        if (tk + 3 < GNT) STAGE(tk + 3, (tk + 3) & 3);

        const unsigned short* As = &ls[tk & 3][0][0];
        const unsigned short* Bs = &ls[tk & 3][1][0];
        short8 af[8], bq[4];
        #pragma unroll
        for (int nt = 0; nt < 4; ++nt)
            bq[nt] = *(const short8*)&Bs[boff + nt * 512];
        #pragma unroll
        for (int mt = 0; mt < 8; ++mt)
            af[mt] = *(const short8*)&As[aoff + mt * 512];

        __builtin_amdgcn_s_setprio(1);
        #pragma unroll
        for (int mt = 0; mt < 8; ++mt)
            #pragma unroll
            for (int nt = 0; nt < 4; ++nt)
                acc[mt][nt] = __builtin_amdgcn_mfma_f32_16x16x32_bf16(
                    af[mt], bq[nt], acc[mt][nt], 0, 0, 0);
        __builtin_amdgcn_s_setprio(0);
    }
    #undef STAGE

    // epilogue: C/D layout col=lane&15, row=quad*4+reg
    #pragma unroll
    for (int mt = 0; mt < 8; ++mt) {
        #pragma unroll
        for (int nt = 0; nt < 4; ++nt) {
            int col = n0 + wn * 64 + nt * 16 + l16;
            float bv = bias[col];
            #pragma unroll
            for (int r = 0; r < 4; ++r) {
                int row = m0 + wm * 128 + mt * 16 + quad * 4 + r;
                float val = acc[mt][nt][r] + bv;
                if (OUT_F32)
                    ((float*)Cp)[(size_t)row * DMODEL + col] = val;
                else
                    ((unsigned short*)Cp)[(size_t)row * DMODEL + col] = f2bf(val);
            }
        }
    }
}

// ---------------- fused attention ------------------------------------------
#define KST 72
#define VST 136
__global__ __launch_bounds__(256) void attn_kernel(
    const unsigned short* __restrict__ qp,   // [L*B, D] bf16
    const unsigned short* __restrict__ kp,   // [S*B, D] bf16
    const unsigned short* __restrict__ vp,   // [S*B, D] bf16
    const int* __restrict__ smp_g,           // [S]
    const int* __restrict__ mkl_g,           // [B]
    unsigned short* __restrict__ ctx)        // [L*B, D] bf16
{
    __shared__ __align__(16) unsigned short kbuf[NSAMP * KST];   // [s][d] padded
    __shared__ __align__(16) unsigned short vT[64 * VST];        // [d][s] padded
    __shared__ __align__(16) unsigned short pbuf[4][16 * VST];   // per-wave P
    __shared__ int smp_s[NSAMP];

    const int t = threadIdx.x;
    const int b = blockIdx.y >> 4, h = blockIdx.y & 15;
    const int wave = t >> 6, lane = t & 63;
    const int l16 = lane & 15, quad = lane >> 4;
    const int Lbase = blockIdx.x * 256;
    const int mkl_b = mkl_g[b];

    #pragma unroll
    for (int p = 0; p < 4; ++p) {
        int c = p * 256 + t;
        int s = c >> 3, d0 = (c & 7) * 8;
        *(uint4*)&kbuf[s * KST + d0] =
            *(const uint4*)&kp[((size_t)(s * BATCH + b)) * DMODEL + h * 64 + d0];
    }
    #pragma unroll
    for (int p = 0; p < 4; ++p) {
        int c = p * 256 + t;
        int s = c >> 3, d0 = (c & 7) * 8;
        uint4 pk = *(const uint4*)&vp[((size_t)(s * BATCH + b)) * DMODEL + h * 64 + d0];
        const unsigned short* e = (const unsigned short*)&pk;
        #pragma unroll
        for (int j = 0; j < 8; ++j) vT[(d0 + j) * VST + s] = e[j];
    }
    if (t < NSAMP) smp_s[t] = smp_g[t];
    __syncthreads();

    short8 kf[8][2];
    #pragma unroll
    for (int nt = 0; nt < 8; ++nt) {
        kf[nt][0] = *(const short8*)&kbuf[(nt * 16 + l16) * KST + quad * 8];
        kf[nt][1] = *(const short8*)&kbuf[(nt * 16 + l16) * KST + 32 + quad * 8];
    }

    const float scale = 0.125f;  // 1/sqrt(64)

    for (int qt = 0; qt < 4; ++qt) {
        const int l0 = Lbase + wave * 64 + qt * 16;

        short8 aq0, aq1;
        {
            const unsigned short* qrow =
                qp + ((size_t)(l0 + l16) * BATCH + b) * DMODEL + h * 64;
            aq0 = *(const short8*)&qrow[quad * 8];
            aq1 = *(const short8*)&qrow[32 + quad * 8];
        }

        f32x4 sc[8];
        #pragma unroll
        for (int nt = 0; nt < 8; ++nt) sc[nt] = f32x4{0.f, 0.f, 0.f, 0.f};
        #pragma unroll
        for (int nt = 0; nt < 8; ++nt) {
            sc[nt] = __builtin_amdgcn_mfma_f32_16x16x32_bf16(aq0, kf[nt][0], sc[nt], 0, 0, 0);
            sc[nt] = __builtin_amdgcn_mfma_f32_16x16x32_bf16(aq1, kf[nt][1], sc[nt], 0, 0, 0);
        }

        #pragma unroll
        for (int nt = 0; nt < 8; ++nt) {
            int s = nt * 16 + l16;
            bool pad = (s >= mkl_b);
            int si = smp_s[s];
            #pragma unroll
            for (int r = 0; r < 4; ++r) {
                int lrow = l0 + quad * 4 + r;
                float v = sc[nt][r] * scale;
                if (pad || si > lrow) v = -INFINITY;
                sc[nt][r] = v;
            }
        }
        #pragma unroll
        for (int r = 0; r < 4; ++r) {
            float mx = sc[0][r];
            #pragma unroll
            for (int nt = 1; nt < 8; ++nt) mx = fmaxf(mx, sc[nt][r]);
            #pragma unroll
            for (int off = 1; off < 16; off <<= 1) mx = fmaxf(mx, __shfl_xor(mx, off));
            float sm = 0.f;
            #pragma unroll
            for (int nt = 0; nt < 8; ++nt) {
                float e = __expf(sc[nt][r] - mx);
                sc[nt][r] = e;
                sm += e;
            }
            #pragma unroll
            for (int off = 1; off < 16; off <<= 1) sm += __shfl_xor(sm, off);
            float inv = 1.0f / sm;
            #pragma unroll
            for (int nt = 0; nt < 8; ++nt) sc[nt][r] *= inv;
        }

        #pragma unroll
        for (int nt = 0; nt < 8; ++nt)
            #pragma unroll
            for (int r = 0; r < 4; ++r)
                pbuf[wave][(quad * 4 + r) * VST + nt * 16 + l16] = f2bf(sc[nt][r]);

        f32x4 oc[4];
        #pragma unroll
        for (int dt = 0; dt < 4; ++dt) oc[dt] = f32x4{0.f, 0.f, 0.f, 0.f};
        #pragma unroll
        for (int s0 = 0; s0 < 128; s0 += 32) {
            short8 ap = *(const short8*)&pbuf[wave][l16 * VST + s0 + quad * 8];
            #pragma unroll
            for (int dt = 0; dt < 4; ++dt) {
                short8 bv = *(const short8*)&vT[(dt * 16 + l16) * VST + s0 + quad * 8];
                oc[dt] = __builtin_amdgcn_mfma_f32_16x16x32_bf16(ap, bv, oc[dt], 0, 0, 0);
            }
        }

        #pragma unroll
        for (int dt = 0; dt < 4; ++dt)
            #pragma unroll
            for (int r = 0; r < 4; ++r) {
                int lrow = l0 + quad * 4 + r;
                ctx[((size_t)lrow * BATCH + b) * DMODEL + h * 64 + dt * 16 + l16] =
                    f2bf(oc[dt][r]);
            }
    }
}

// ---------------------------------------------------------------------------
extern "C" void kernel_launch(void* const* d_in, const int* in_sizes, int n_in,
                              void* d_out, int out_size, void* d_ws, size_t ws_size,
                              hipStream_t stream) {
    const float* q    = (const float*)d_in[0];
    const float* k    = (const float*)d_in[1];
    const float* v    = (const float*)d_in[2];
    const int*   klen = (const int*)d_in[3];
    const int*   smp  = (const int*)d_in[4];
    const float* ipw  = (const float*)d_in[5];
    const float* ipb  = (const float*)d_in[6];
    const float* ow   = (const float*)d_in[7];
    const float* ob   = (const float*)d_in[8];
    float* out = (float*)d_out;

    char* ws = (char*)d_ws;
    size_t off = 0;
    auto alloc = [&](size_t bytes) -> void* {
        void* p = ws + off;
        off += (bytes + 255) & ~(size_t)255;
        return p;
    };
    unsigned short* w_bf  = (unsigned short*)alloc((size_t)3 * 1024 * 1024 * 2);
    unsigned short* ow_bf = (unsigned short*)alloc((size_t)1024 * 1024 * 2);
    unsigned short* ks_bf = (unsigned short*)alloc((size_t)NSAMP * BATCH * DMODEL * 2);
    unsigned short* vs_bf = (unsigned short*)alloc((size_t)NSAMP * BATCH * DMODEL * 2);
    unsigned short* q_bf  = (unsigned short*)alloc((size_t)L_SEQ * BATCH * DMODEL * 2);
    unsigned short* qp    = (unsigned short*)alloc((size_t)L_SEQ * BATCH * DMODEL * 2);
    unsigned short* kpp   = (unsigned short*)alloc((size_t)NSAMP * BATCH * DMODEL * 2);
    unsigned short* vpp   = (unsigned short*)alloc((size_t)NSAMP * BATCH * DMODEL * 2);
    int*            mkl   = (int*)alloc(256);
    // ctx aliases q_bf (q_bf dead after qp GEMM; attn runs strictly after)
    unsigned short* ctx = q_bf;

    // conversions
    conv_bf16_kernel<<<32768, 256, 0, stream>>>(q, q_bf, L_SEQ * BATCH * DMODEL / 4);
    conv_bf16_kernel<<<3072, 256, 0, stream>>>(ipw, w_bf, 3 * 1024 * 1024 / 4);
    conv_bf16_kernel<<<1024, 256, 0, stream>>>(ow, ow_bf, 1024 * 1024 / 4);
    // gathers (f32 -> bf16)
    gather_bf16_kernel<<<512, 256, 0, stream>>>(k, smp, ks_bf, NSAMP * BATCH * DMODEL / 8);
    gather_bf16_kernel<<<512, 256, 0, stream>>>(v, smp, vs_bf, NSAMP * BATCH * DMODEL / 8);
    mkl_kernel<<<1, 64, 0, stream>>>(smp, klen, mkl);

    // Q projection: [32768,1024] x [1024,1024]^T  (new pipelined 256^2 GEMM)
    gemm256_kernel<false><<<dim3(512), 512, 0, stream>>>(q_bf, w_bf, ipb, qp);
    // K/V projections fused (small M; old path)
    gemm_kv<<<dim3(8, 8, 2), 256, 0, stream>>>(
        ks_bf, vs_bf, w_bf + (size_t)1024 * 1024, w_bf + (size_t)2 * 1024 * 1024,
        ipb + 1024, ipb + 2048, kpp, vpp);

    // attention
    attn_kernel<<<dim3(L_SEQ / 256, BATCH * NHEAD), 256, 0, stream>>>(
        qp, kpp, vpp, smp, mkl, ctx);

    // output projection -> f32 (new pipelined 256^2 GEMM)
    gemm256_kernel<true><<<dim3(512), 512, 0, stream>>>(ctx, ow_bf, ob, out);
}

// Round 2
// 584.711 us; speedup vs baseline: 1.1274x; 1.0294x over previous
//
#include <hip/hip_runtime.h>
#include <hip/hip_bf16.h>

#define L_SEQ 4096
#define BATCH 8
#define DMODEL 1024
#define NHEAD 16
#define DHEAD 64
#define NSAMP 128

typedef __attribute__((ext_vector_type(8))) short short8;
typedef __attribute__((ext_vector_type(4))) float f32x4;

static __device__ __forceinline__ unsigned short f2bf(float f) {
    union { float f; unsigned int u; } x; x.f = f;
    unsigned int r = (x.u + 0x7fffu + ((x.u >> 16) & 1u)) >> 16;
    return (unsigned short)r;
}

// async global->LDS, 16B per lane; LDS dest must be wave-uniform-base + lane*16
static __device__ __forceinline__ void gld_lds16(const unsigned short* g,
                                                 unsigned short* l) {
    __builtin_amdgcn_global_load_lds(
        (const __attribute__((address_space(1))) void*)g,
        (__attribute__((address_space(3))) void*)l, 16, 0, 0);
}

// ---------------- elementwise f32 -> bf16 convert (float4 granularity) ------
__global__ void conv_bf16_kernel(const float* __restrict__ src,
                                 unsigned short* __restrict__ dst, int n4) {
    int idx = blockIdx.x * blockDim.x + threadIdx.x;
    if (idx < n4) {
        float4 v = ((const float4*)src)[idx];
        uint2 pk;
        pk.x = (unsigned)f2bf(v.x) | ((unsigned)f2bf(v.y) << 16);
        pk.y = (unsigned)f2bf(v.z) | ((unsigned)f2bf(v.w) << 16);
        ((uint2*)dst)[idx] = pk;
    }
}

// ---------------- gather rows of k/v by sampled_index -> bf16 ---------------
__global__ void gather_bf16_kernel(const float* __restrict__ src,
                                   const int* __restrict__ smp,
                                   unsigned short* __restrict__ dst, int total8) {
    int idx = blockIdx.x * blockDim.x + threadIdx.x;
    if (idx < total8) {
        int s = idx >> 10;
        int rem = idx & 1023;
        const float* g = src + (size_t)smp[s] * (BATCH * DMODEL) + rem * 8;
        float4 v0 = *(const float4*)g;
        float4 v1 = *(const float4*)(g + 4);
        uint4 pk;
        pk.x = (unsigned)f2bf(v0.x) | ((unsigned)f2bf(v0.y) << 16);
        pk.y = (unsigned)f2bf(v0.z) | ((unsigned)f2bf(v0.w) << 16);
        pk.z = (unsigned)f2bf(v1.x) | ((unsigned)f2bf(v1.y) << 16);
        pk.w = (unsigned)f2bf(v1.z) | ((unsigned)f2bf(v1.w) << 16);
        *(uint4*)&dst[(size_t)idx * 8] = pk;
    }
}

// ---------------- modify_key_length ----------------------------------------
__global__ void mkl_kernel(const int* __restrict__ smp,
                           const int* __restrict__ klen, int* __restrict__ mkl) {
    int b = threadIdx.x;
    if (b < BATCH) {
        int kl = klen[b];
        int c = 0;
        for (int s = 0; s < NSAMP; ++s) c += (smp[s] < kl) ? 1 : 0;
        mkl[b] = c;
    }
}

// ---------------- old 128x128 NT GEMM body (kept for small K/V proj) -------
template <bool OUT_F32>
static __device__ __forceinline__ void gemm_body(
    const unsigned short* __restrict__ A, const unsigned short* __restrict__ Bw,
    const float* __restrict__ bias, void* __restrict__ Cp,
    int m0, int n0, int N, int K,
    unsigned short* lA, unsigned short* lB) {
    const int t = threadIdx.x;
    const int wave = t >> 6;
    const int lane = t & 63;
    const int l16 = lane & 15;
    const int quad = lane >> 4;
    const int wm = (wave >> 1) * 64;
    const int wn = (wave & 1) * 64;

    f32x4 acc[4][4];
    #pragma unroll
    for (int i = 0; i < 4; ++i)
        #pragma unroll
        for (int j = 0; j < 4; ++j)
            acc[i][j] = f32x4{0.f, 0.f, 0.f, 0.f};

    const int lin0 = t * 8;
    const int wbase = (t & ~63) * 8;

    for (int k0 = 0; k0 < K; k0 += 64) {
        #pragma unroll
        for (int p = 0; p < 4; ++p) {
            int lin = p * 2048 + lin0;
            int row = lin >> 6, col = lin & 63;
            gld_lds16(A + (size_t)(m0 + row) * K + k0 + col, lA + p * 2048 + wbase);
        }
        #pragma unroll
        for (int p = 0; p < 4; ++p) {
            int lin = p * 2048 + lin0;
            int row = lin >> 6, col = lin & 63;
            gld_lds16(Bw + (size_t)(n0 + row) * K + k0 + col, lB + p * 2048 + wbase);
        }
        __syncthreads();

        #pragma unroll
        for (int kk = 0; kk < 64; kk += 32) {
            short8 af[4], bfr[4];
            #pragma unroll
            for (int mt = 0; mt < 4; ++mt)
                af[mt] = *(const short8*)&lA[(wm + mt * 16 + l16) * 64 + kk + quad * 8];
            #pragma unroll
            for (int nt = 0; nt < 4; ++nt)
                bfr[nt] = *(const short8*)&lB[(wn + nt * 16 + l16) * 64 + kk + quad * 8];
            #pragma unroll
            for (int mt = 0; mt < 4; ++mt)
                #pragma unroll
                for (int nt = 0; nt < 4; ++nt)
                    acc[mt][nt] = __builtin_amdgcn_mfma_f32_16x16x32_bf16(
                        af[mt], bfr[nt], acc[mt][nt], 0, 0, 0);
        }
        __syncthreads();
    }

    #pragma unroll
    for (int mt = 0; mt < 4; ++mt) {
        #pragma unroll
        for (int nt = 0; nt < 4; ++nt) {
            int col = n0 + wn + nt * 16 + l16;
            float bv = bias[col];
            #pragma unroll
            for (int r = 0; r < 4; ++r) {
                int row = m0 + wm + mt * 16 + quad * 4 + r;
                float val = acc[mt][nt][r] + bv;
                if (OUT_F32)
                    ((float*)Cp)[(size_t)row * N + col] = val;
                else
                    ((unsigned short*)Cp)[(size_t)row * N + col] = f2bf(val);
            }
        }
    }
}

// fused K/V projection: z=0 -> kp, z=1 -> vp (small M=1024; old path)
__global__ __launch_bounds__(256) void gemm_kv(
    const unsigned short* __restrict__ Ak, const unsigned short* __restrict__ Av,
    const unsigned short* __restrict__ Bk, const unsigned short* __restrict__ Bv,
    const float* __restrict__ bk, const float* __restrict__ bv,
    unsigned short* __restrict__ Ck, unsigned short* __restrict__ Cv) {
    __shared__ __align__(16) unsigned short lA[128 * 64];
    __shared__ __align__(16) unsigned short lB[128 * 64];
    if (blockIdx.z == 0)
        gemm_body<false>(Ak, Bk, bk, Ck, blockIdx.x * 128, blockIdx.y * 128,
                         DMODEL, DMODEL, lA, lB);
    else
        gemm_body<false>(Av, Bv, bv, Cv, blockIdx.x * 128, blockIdx.y * 128,
                         DMODEL, DMODEL, lA, lB);
}

// ---------------- 256x256 8-phase pipelined NT GEMM (m201-style) -----------
// M=32768, N=K=1024. 512 thr = 8 waves (2M x 4N), wave tile 128x64. BK=64.
// LDS: dbuf x {A,B} x [256][64] bf16 = 128 KiB. Chunk swizzle within a row:
// c' = c ^ (row&7) (c = 16B chunk, 8 per row) -> every ds_read_b128 fragment
// read is 2 lanes/bank (free). Staging keeps LINEAR LDS dest (rule: gld_lds
// writes wave-uniform-base + lane*16) and pre-swizzles the GLOBAL source.
// 4 phases per K-tile, each: {ds-read subtile | 2x gld_lds -> barrier ->
// lgkmcnt(0) -> setprio+16 MFMA -> counted vmcnt -> barrier}.
// Stage groups for tile t+1: ph0:A-lo ph1:B-lo ph2:B-hi ph3:A-hi.
// Consumed at t+1: ph0 reads {A-lo,B-lo}, ph1 {B-hi}, ph2 {A-hi}.
// Guarantee (vmcnt BEFORE a barrier => cross-wave safe after it):
//   A-lo,B-lo : vmcnt(4) @ ph3(t) end   (after B-lo: B-hi[2]+A-hi[2]=4)
//   B-hi      : vmcnt(4) @ ph0(t+1) end (after: A-hi[2]+A-lo(t+2)[2]=4)
//   A-hi      : vmcnt(4) @ ph1(t+1) end (after: A-lo(t+2)[2]+B-lo(t+2)[2]=4)
// Last tile (no staging): counts become {2, 0}.
#define GNT 16   // K / 64

template <bool OUT_F32>
__global__ __launch_bounds__(512, 2) void gemm256_kernel(
    const unsigned short* __restrict__ A, const unsigned short* __restrict__ Bw,
    const float* __restrict__ bias, void* __restrict__ Cp)
{
    __shared__ __align__(16) unsigned short ls[2][2][256 * 64];  // 128 KiB

    const int bid = blockIdx.x;
    const int swz = (bid & 7) * 64 + (bid >> 3);   // bijective: 512 = 8*64
    const int m0 = (swz >> 2) * 256;
    const int n0 = (swz & 3) * 256;

    const int t = threadIdx.x;
    const int w = t >> 6, lane = t & 63;
    const int l16 = lane & 15, quad = lane >> 4;
    const int wm = w >> 2, wn = w & 3;
    const int s8 = l16 & 7;                       // read-side swizzle key
    const int lr = lane >> 3;                     // 0..7 row within wave group
    const int kswz = ((lane & 7) ^ lr) * 8;       // source-side swizzle (elems)

    // global source row indices (per thread) for the 8 stage loads
    const int rA0 = w * 8 + lr;                   // A rows   0..63
    const int rA1 = 128 + w * 8 + lr;             // A rows 128..191
    const int rA2 = 64 + w * 8 + lr;              // A rows  64..127
    const int rA3 = 192 + w * 8 + lr;             // A rows 192..255
    const int blo = w * 8 + (w >= 4 ? 32 : 0);
    const int rB0 = blo + lr;                     // B rows {0-31,64-95}
    const int rB1 = blo + 128 + lr;               // B rows {128-159,192-223}
    const int rB2 = blo + 32 + lr;                // B rows {32-63,96-127}
    const int rB3 = blo + 160 + lr;               // B rows {160-191,224-255}

    const unsigned short* pA0 = A + (size_t)(m0 + rA0) * DMODEL + kswz;
    const unsigned short* pA1 = A + (size_t)(m0 + rA1) * DMODEL + kswz;
    const unsigned short* pA2 = A + (size_t)(m0 + rA2) * DMODEL + kswz;
    const unsigned short* pA3 = A + (size_t)(m0 + rA3) * DMODEL + kswz;
    const unsigned short* pB0 = Bw + (size_t)(n0 + rB0) * DMODEL + kswz;
    const unsigned short* pB1 = Bw + (size_t)(n0 + rB1) * DMODEL + kswz;
    const unsigned short* pB2 = Bw + (size_t)(n0 + rB2) * DMODEL + kswz;
    const unsigned short* pB3 = Bw + (size_t)(n0 + rB3) * DMODEL + kswz;

    // wave-uniform LDS dest bases (element offsets; lane*8 added by HW)
    const int dA0 = (rA0 - lr) * 64;
    const int dA1 = (rA1 - lr) * 64;
    const int dA2 = (rA2 - lr) * 64;
    const int dA3 = (rA3 - lr) * 64;
    const int dB0 = (rB0 - lr) * 64;
    const int dB1 = (rB1 - lr) * 64;
    const int dB2 = (rB2 - lr) * 64;
    const int dB3 = (rB3 - lr) * 64;

    f32x4 acc[8][4];
    #pragma unroll
    for (int i = 0; i < 8; ++i)
        #pragma unroll
        for (int j = 0; j < 4; ++j)
            acc[i][j] = f32x4{0.f, 0.f, 0.f, 0.f};

    short8 aq[8];       // current m-half: 4 mt x 2 kk
    short8 bq[2][4];    // both n-halves: 2 nt x 2 kk each

    auto rd_a = [&](const unsigned short* As, int mbase) {
        #pragma unroll
        for (int mt = 0; mt < 4; ++mt)
            #pragma unroll
            for (int kk = 0; kk < 2; ++kk)
                aq[mt * 2 + kk] = *(const short8*)&As[
                    (wm * 128 + (mbase + mt) * 16 + l16) * 64 +
                    ((kk * 4 + quad) ^ s8) * 8];
    };
    auto rd_b = [&](int nh, const unsigned short* Bs) {
        #pragma unroll
        for (int nt = 0; nt < 2; ++nt)
            #pragma unroll
            for (int kk = 0; kk < 2; ++kk)
                bq[nh][nt * 2 + kk] = *(const short8*)&Bs[
                    (wn * 64 + (nh * 2 + nt) * 16 + l16) * 64 +
                    ((kk * 4 + quad) ^ s8) * 8];
    };
    auto mm = [&](int mh, int nh) {
        #pragma unroll
        for (int kk = 0; kk < 2; ++kk)
            #pragma unroll
            for (int mt = 0; mt < 4; ++mt)
                #pragma unroll
                for (int nt = 0; nt < 2; ++nt)
                    acc[mh * 4 + mt][nh * 2 + nt] =
                        __builtin_amdgcn_mfma_f32_16x16x32_bf16(
                            aq[mt * 2 + kk], bq[nh][nt * 2 + kk],
                            acc[mh * 4 + mt][nh * 2 + nt], 0, 0, 0);
    };

    // prologue: stage tile 0 (issue order = steady-state order), advance ptrs
    gld_lds16(pA0, &ls[0][0][dA0]); gld_lds16(pA1, &ls[0][0][dA1]);
    gld_lds16(pB0, &ls[0][1][dB0]); gld_lds16(pB1, &ls[0][1][dB1]);
    gld_lds16(pB2, &ls[0][1][dB2]); gld_lds16(pB3, &ls[0][1][dB3]);
    gld_lds16(pA2, &ls[0][0][dA2]); gld_lds16(pA3, &ls[0][0][dA3]);
    pA0 += 64; pA1 += 64; pA2 += 64; pA3 += 64;
    pB0 += 64; pB1 += 64; pB2 += 64; pB3 += 64;
    asm volatile("s_waitcnt vmcnt(4)" ::: "memory");   // A-lo,B-lo landed
    __builtin_amdgcn_s_barrier();

#define TILE_BODY(CUR, DO_STAGE, VM_A, VM_B, VM_C)                             \
  {                                                                            \
    const unsigned short* As = &ls[CUR][0][0];                                 \
    const unsigned short* Bs = &ls[CUR][1][0];                                 \
    const int nx = (CUR) ^ 1;                                                  \
    /* phase 0: read A-lo + B-lo, stage A-lo(next) */                          \
    rd_a(As, 0);                                                               \
    rd_b(0, Bs);                                                               \
    if (DO_STAGE) { gld_lds16(pA0, &ls[nx][0][dA0]);                           \
                    gld_lds16(pA1, &ls[nx][0][dA1]); }                         \
    asm volatile("s_waitcnt lgkmcnt(8)" ::: "memory");                         \
    __builtin_amdgcn_s_barrier();                                              \
    asm volatile("s_waitcnt lgkmcnt(0)" ::: "memory");                         \
    __builtin_amdgcn_s_setprio(1); mm(0, 0); __builtin_amdgcn_s_setprio(0);    \
    asm volatile("s_waitcnt vmcnt(" VM_A ")" ::: "memory");                    \
    __builtin_amdgcn_s_barrier();                                              \
    /* phase 1: read B-hi, stage B-lo(next) */                                 \
    rd_b(1, Bs);                                                               \
    if (DO_STAGE) { gld_lds16(pB0, &ls[nx][1][dB0]);                           \
                    gld_lds16(pB1, &ls[nx][1][dB1]); }                         \
    __builtin_amdgcn_s_barrier();                                              \
    asm volatile("s_waitcnt lgkmcnt(0)" ::: "memory");                         \
    __builtin_amdgcn_s_setprio(1); mm(0, 1); __builtin_amdgcn_s_setprio(0);    \
    asm volatile("s_waitcnt vmcnt(" VM_B ")" ::: "memory");                    \
    __builtin_amdgcn_s_barrier();                                              \
    /* phase 2: read A-hi, stage B-hi(next) */                                 \
    rd_a(As, 4);                                                               \
    if (DO_STAGE) { gld_lds16(pB2, &ls[nx][1][dB2]);                           \
                    gld_lds16(pB3, &ls[nx][1][dB3]); }                         \
    __builtin_amdgcn_s_barrier();                                              \
    asm volatile("s_waitcnt lgkmcnt(0)" ::: "memory");                         \
    __builtin_amdgcn_s_setprio(1); mm(1, 0); __builtin_amdgcn_s_setprio(0);    \
    __builtin_amdgcn_s_barrier();                                              \
    /* phase 3: stage A-hi(next), compute from regs */                         \
    if (DO_STAGE) { gld_lds16(pA2, &ls[nx][0][dA2]);                           \
                    gld_lds16(pA3, &ls[nx][0][dA3]); }                         \
    __builtin_amdgcn_s_barrier();                                              \
    __builtin_amdgcn_s_setprio(1); mm(1, 1); __builtin_amdgcn_s_setprio(0);    \
    if (VM_C) { asm volatile("s_waitcnt vmcnt(4)" ::: "memory"); }             \
    __builtin_amdgcn_s_barrier();                                              \
  }

    int cur = 0;
    #pragma unroll 1
    for (int tt = 0; tt < GNT - 1; ++tt) {
        TILE_BODY(cur, true, "4", "4", true);
        pA0 += 64; pA1 += 64; pA2 += 64; pA3 += 64;
        pB0 += 64; pB1 += 64; pB2 += 64; pB3 += 64;
        cur ^= 1;
    }
    TILE_BODY(cur, false, "2", "0", false);
#undef TILE_BODY

    // epilogue: C/D layout col=lane&15, row=quad*4+reg
    #pragma unroll
    for (int mt = 0; mt < 8; ++mt) {
        #pragma unroll
        for (int nt = 0; nt < 4; ++nt) {
            int col = n0 + wn * 64 + nt * 16 + l16;
            float bv = bias[col];
            #pragma unroll
            for (int r = 0; r < 4; ++r) {
                int row = m0 + wm * 128 + mt * 16 + quad * 4 + r;
                float val = acc[mt][nt][r] + bv;
                if (OUT_F32)
                    ((float*)Cp)[(size_t)row * DMODEL + col] = val;
                else
                    ((unsigned short*)Cp)[(size_t)row * DMODEL + col] = f2bf(val);
            }
        }
    }
}

// ---------------- fused attention ------------------------------------------
#define KST 72
#define VST 136
__global__ __launch_bounds__(256) void attn_kernel(
    const unsigned short* __restrict__ qp,   // [L*B, D] bf16
    const unsigned short* __restrict__ kp,   // [S*B, D] bf16
    const unsigned short* __restrict__ vp,   // [S*B, D] bf16
    const int* __restrict__ smp_g,           // [S]
    const int* __restrict__ mkl_g,           // [B]
    unsigned short* __restrict__ ctx)        // [L*B, D] bf16
{
    __shared__ __align__(16) unsigned short kbuf[NSAMP * KST];   // [s][d] padded
    __shared__ __align__(16) unsigned short vT[64 * VST];        // [d][s] padded
    __shared__ __align__(16) unsigned short pbuf[4][16 * VST];   // per-wave P
    __shared__ int smp_s[NSAMP];

    const int t = threadIdx.x;
    const int b = blockIdx.y >> 4, h = blockIdx.y & 15;
    const int wave = t >> 6, lane = t & 63;
    const int l16 = lane & 15, quad = lane >> 4;
    const int Lbase = blockIdx.x * 256;
    const int mkl_b = mkl_g[b];

    #pragma unroll
    for (int p = 0; p < 4; ++p) {
        int c = p * 256 + t;
        int s = c >> 3, d0 = (c & 7) * 8;
        *(uint4*)&kbuf[s * KST + d0] =
            *(const uint4*)&kp[((size_t)(s * BATCH + b)) * DMODEL + h * 64 + d0];
    }
    #pragma unroll
    for (int p = 0; p < 4; ++p) {
        int c = p * 256 + t;
        int s = c >> 3, d0 = (c & 7) * 8;
        uint4 pk = *(const uint4*)&vp[((size_t)(s * BATCH + b)) * DMODEL + h * 64 + d0];
        const unsigned short* e = (const unsigned short*)&pk;
        #pragma unroll
        for (int j = 0; j < 8; ++j) vT[(d0 + j) * VST + s] = e[j];
    }
    if (t < NSAMP) smp_s[t] = smp_g[t];
    __syncthreads();

    short8 kf[8][2];
    #pragma unroll
    for (int nt = 0; nt < 8; ++nt) {
        kf[nt][0] = *(const short8*)&kbuf[(nt * 16 + l16) * KST + quad * 8];
        kf[nt][1] = *(const short8*)&kbuf[(nt * 16 + l16) * KST + 32 + quad * 8];
    }

    const float scale = 0.125f;  // 1/sqrt(64)

    for (int qt = 0; qt < 4; ++qt) {
        const int l0 = Lbase + wave * 64 + qt * 16;

        short8 aq0, aq1;
        {
            const unsigned short* qrow =
                qp + ((size_t)(l0 + l16) * BATCH + b) * DMODEL + h * 64;
            aq0 = *(const short8*)&qrow[quad * 8];
            aq1 = *(const short8*)&qrow[32 + quad * 8];
        }

        f32x4 sc[8];
        #pragma unroll
        for (int nt = 0; nt < 8; ++nt) sc[nt] = f32x4{0.f, 0.f, 0.f, 0.f};
        #pragma unroll
        for (int nt = 0; nt < 8; ++nt) {
            sc[nt] = __builtin_amdgcn_mfma_f32_16x16x32_bf16(aq0, kf[nt][0], sc[nt], 0, 0, 0);
            sc[nt] = __builtin_amdgcn_mfma_f32_16x16x32_bf16(aq1, kf[nt][1], sc[nt], 0, 0, 0);
        }

        #pragma unroll
        for (int nt = 0; nt < 8; ++nt) {
            int s = nt * 16 + l16;
            bool pad = (s >= mkl_b);
            int si = smp_s[s];
            #pragma unroll
            for (int r = 0; r < 4; ++r) {
                int lrow = l0 + quad * 4 + r;
                float v = sc[nt][r] * scale;
                if (pad || si > lrow) v = -INFINITY;
                sc[nt][r] = v;
            }
        }
        #pragma unroll
        for (int r = 0; r < 4; ++r) {
            float mx = sc[0][r];
            #pragma unroll
            for (int nt = 1; nt < 8; ++nt) mx = fmaxf(mx, sc[nt][r]);
            #pragma unroll
            for (int off = 1; off < 16; off <<= 1) mx = fmaxf(mx, __shfl_xor(mx, off));
            float sm = 0.f;
            #pragma unroll
            for (int nt = 0; nt < 8; ++nt) {
                float e = __expf(sc[nt][r] - mx);
                sc[nt][r] = e;
                sm += e;
            }
            #pragma unroll
            for (int off = 1; off < 16; off <<= 1) sm += __shfl_xor(sm, off);
            float inv = 1.0f / sm;
            #pragma unroll
            for (int nt = 0; nt < 8; ++nt) sc[nt][r] *= inv;
        }

        #pragma unroll
        for (int nt = 0; nt < 8; ++nt)
            #pragma unroll
            for (int r = 0; r < 4; ++r)
                pbuf[wave][(quad * 4 + r) * VST + nt * 16 + l16] = f2bf(sc[nt][r]);

        f32x4 oc[4];
        #pragma unroll
        for (int dt = 0; dt < 4; ++dt) oc[dt] = f32x4{0.f, 0.f, 0.f, 0.f};
        #pragma unroll
        for (int s0 = 0; s0 < 128; s0 += 32) {
            short8 ap = *(const short8*)&pbuf[wave][l16 * VST + s0 + quad * 8];
            #pragma unroll
            for (int dt = 0; dt < 4; ++dt) {
                short8 bv = *(const short8*)&vT[(dt * 16 + l16) * VST + s0 + quad * 8];
                oc[dt] = __builtin_amdgcn_mfma_f32_16x16x32_bf16(ap, bv, oc[dt], 0, 0, 0);
            }
        }

        #pragma unroll
        for (int dt = 0; dt < 4; ++dt)
            #pragma unroll
            for (int r = 0; r < 4; ++r) {
                int lrow = l0 + quad * 4 + r;
                ctx[((size_t)lrow * BATCH + b) * DMODEL + h * 64 + dt * 16 + l16] =
                    f2bf(oc[dt][r]);
            }
    }
}

// ---------------------------------------------------------------------------
extern "C" void kernel_launch(void* const* d_in, const int* in_sizes, int n_in,
                              void* d_out, int out_size, void* d_ws, size_t ws_size,
                              hipStream_t stream) {
    const float* q    = (const float*)d_in[0];
    const float* k    = (const float*)d_in[1];
    const float* v    = (const float*)d_in[2];
    const int*   klen = (const int*)d_in[3];
    const int*   smp  = (const int*)d_in[4];
    const float* ipw  = (const float*)d_in[5];
    const float* ipb  = (const float*)d_in[6];
    const float* ow   = (const float*)d_in[7];
    const float* ob   = (const float*)d_in[8];
    float* out = (float*)d_out;

    char* ws = (char*)d_ws;
    size_t off = 0;
    auto alloc = [&](size_t bytes) -> void* {
        void* p = ws + off;
        off += (bytes + 255) & ~(size_t)255;
        return p;
    };
    unsigned short* w_bf  = (unsigned short*)alloc((size_t)3 * 1024 * 1024 * 2);
    unsigned short* ow_bf = (unsigned short*)alloc((size_t)1024 * 1024 * 2);
    unsigned short* ks_bf = (unsigned short*)alloc((size_t)NSAMP * BATCH * DMODEL * 2);
    unsigned short* vs_bf = (unsigned short*)alloc((size_t)NSAMP * BATCH * DMODEL * 2);
    unsigned short* q_bf  = (unsigned short*)alloc((size_t)L_SEQ * BATCH * DMODEL * 2);
    unsigned short* qp    = (unsigned short*)alloc((size_t)L_SEQ * BATCH * DMODEL * 2);
    unsigned short* kpp   = (unsigned short*)alloc((size_t)NSAMP * BATCH * DMODEL * 2);
    unsigned short* vpp   = (unsigned short*)alloc((size_t)NSAMP * BATCH * DMODEL * 2);
    int*            mkl   = (int*)alloc(256);
    // ctx aliases q_bf (q_bf dead after qp GEMM; attn runs strictly after)
    unsigned short* ctx = q_bf;

    // conversions
    conv_bf16_kernel<<<32768, 256, 0, stream>>>(q, q_bf, L_SEQ * BATCH * DMODEL / 4);
    conv_bf16_kernel<<<3072, 256, 0, stream>>>(ipw, w_bf, 3 * 1024 * 1024 / 4);
    conv_bf16_kernel<<<1024, 256, 0, stream>>>(ow, ow_bf, 1024 * 1024 / 4);
    // gathers (f32 -> bf16)
    gather_bf16_kernel<<<512, 256, 0, stream>>>(k, smp, ks_bf, NSAMP * BATCH * DMODEL / 8);
    gather_bf16_kernel<<<512, 256, 0, stream>>>(v, smp, vs_bf, NSAMP * BATCH * DMODEL / 8);
    mkl_kernel<<<1, 64, 0, stream>>>(smp, klen, mkl);

    // Q projection: [32768,1024] x [1024,1024]^T  (8-phase 256^2 GEMM)
    gemm256_kernel<false><<<dim3(512), 512, 0, stream>>>(q_bf, w_bf, ipb, qp);
    // K/V projections fused (small M; old path)
    gemm_kv<<<dim3(8, 8, 2), 256, 0, stream>>>(
        ks_bf, vs_bf, w_bf + (size_t)1024 * 1024, w_bf + (size_t)2 * 1024 * 1024,
        ipb + 1024, ipb + 2048, kpp, vpp);

    // attention
    attn_kernel<<<dim3(L_SEQ / 256, BATCH * NHEAD), 256, 0, stream>>>(
        qp, kpp, vpp, smp, mkl, ctx);

    // output projection -> f32 (8-phase 256^2 GEMM)
    gemm256_kernel<true><<<dim3(512), 512, 0, stream>>>(ctx, ow_bf, ob, out);
}